// Round 2
// baseline (870.976 us; speedup 1.0000x reference)
//
#include <hip/hip_runtime.h>

#define NN 100000
#define EE 1600000
#define GG 64
#define HH 128
#define BN_EPS 1e-5f

// ---------------- graph prep ----------------

__global__ void k_count(const int* __restrict__ ei, int* __restrict__ cnt) {
    int e = blockIdx.x * blockDim.x + threadIdx.x;
    if (e < EE) atomicAdd(&cnt[ei[EE + e]], 1);
}

__global__ void k_dinv(const int* __restrict__ cnt, float* __restrict__ dinv) {
    int n = blockIdx.x * blockDim.x + threadIdx.x;
    if (n < NN) dinv[n] = rsqrtf((float)(cnt[n] + 1));   // +1 self loop; deg>=1 always
}

// exclusive scan of cnt -> offs, 1024 elems/block
__global__ void k_scan1(const int* __restrict__ cnt, int* __restrict__ offs,
                        int* __restrict__ bsum) {
    __shared__ int sh[256];
    int t = threadIdx.x;
    int base = blockIdx.x * 1024 + t * 4;
    int v0 = (base + 0 < NN) ? cnt[base + 0] : 0;
    int v1 = (base + 1 < NN) ? cnt[base + 1] : 0;
    int v2 = (base + 2 < NN) ? cnt[base + 2] : 0;
    int v3 = (base + 3 < NN) ? cnt[base + 3] : 0;
    int s0 = v0, s1 = s0 + v1, s2 = s1 + v2, s3 = s2 + v3;
    sh[t] = s3; __syncthreads();
    for (int d = 1; d < 256; d <<= 1) {
        int x = (t >= d) ? sh[t - d] : 0;
        __syncthreads();
        sh[t] += x;
        __syncthreads();
    }
    int excl = (t > 0) ? sh[t - 1] : 0;
    if (base + 0 < NN) offs[base + 0] = excl;
    if (base + 1 < NN) offs[base + 1] = excl + s0;
    if (base + 2 < NN) offs[base + 2] = excl + s1;
    if (base + 3 < NN) offs[base + 3] = excl + s2;
    if (t == 255) bsum[blockIdx.x] = sh[255];
}

__global__ void k_scan2(int* __restrict__ bsum, int nblk) {
    __shared__ int sh[128];
    int t = threadIdx.x;
    int v = (t < nblk) ? bsum[t] : 0;
    sh[t] = v; __syncthreads();
    for (int d = 1; d < 128; d <<= 1) {
        int x = (t >= d) ? sh[t - d] : 0;
        __syncthreads();
        sh[t] += x;
        __syncthreads();
    }
    int excl = (t > 0) ? sh[t - 1] : 0;
    if (t < nblk) bsum[t] = excl;
}

__global__ void k_scan3(int* __restrict__ offs, const int* __restrict__ bsum) {
    int i = blockIdx.x * blockDim.x + threadIdx.x;
    if (i < NN) offs[i] += bsum[i >> 10];
}

// bucket edges into CSR (packed src+weight, one 8B store) AND fuse the
// layer-1 input aggregation (3-dim) as L2-resident atomics.
__global__ void k_bucket(const int* __restrict__ ei, const int* __restrict__ offs,
                         int* __restrict__ cursor, const float* __restrict__ dinv,
                         const float* __restrict__ x,
                         int2* __restrict__ meta, float4* __restrict__ agg) {
    int e = blockIdx.x * blockDim.x + threadIdx.x;
    if (e >= EE) return;
    int s = ei[e];
    int d = ei[EE + e];
    float w = dinv[s] * dinv[d];
    int p = offs[d] + atomicAdd(&cursor[d], 1);
    int2 pk; pk.x = s; pk.y = __float_as_int(w);
    meta[p] = pk;
    // layer-1 aggregation in input space (3 dims): agg[d] += w * x[s]
    float x0 = x[s * 3 + 0], x1 = x[s * 3 + 1], x2 = x[s * 3 + 2];
    float* ag = (float*)&agg[d];
    atomicAdd(ag + 0, w * x0);
    atomicAdd(ag + 1, w * x1);
    atomicAdd(ag + 2, w * x2);
}

// ---------------- layer 1: (agg + self) @ W1 + bias + BN + ReLU ----------------

#define L1R 16
__global__ void k_l1(const float4* __restrict__ agg, const float* __restrict__ x,
                     const float* __restrict__ dinv,
                     const float* __restrict__ W1,
                     const float* __restrict__ b1, const float* __restrict__ g,
                     const float* __restrict__ bb, const float* __restrict__ m,
                     const float* __restrict__ v, float* __restrict__ out) {
    int c = threadIdx.x;                       // 0..127
    float w0 = W1[c], w1 = W1[128 + c], w2 = W1[256 + c];
    float sc = g[c] * rsqrtf(v[c] + BN_EPS);
    float sh = (b1[c] - m[c]) * sc + bb[c];
    int r0 = blockIdx.x * L1R;
    for (int i = 0; i < L1R; i++) {
        int n = r0 + i;
        if (n >= NN) break;
        float4 a = agg[n];
        float dv = dinv[n];
        float w2s = dv * dv;
        float ax = a.x + w2s * x[n * 3 + 0];
        float ay = a.y + w2s * x[n * 3 + 1];
        float az = a.z + w2s * x[n * 3 + 2];
        float t = ax * w0 + ay * w1 + az * w2;
        t = t * sc + sh;
        out[n * HH + c] = fmaxf(t, 0.f);
    }
}

// ---------------- dense 128x128 matmul (fp32 vector) ----------------
// 64 rows x 128 cols per block, 256 threads, thread = 8 rows x 4 cols
// LDS padded to 132 floats/row: bank = (4r+k)%32, consecutive rows distinct.

__global__ __launch_bounds__(256) void k_mm(const float* __restrict__ xin,
                                            const float* __restrict__ W,
                                            float* __restrict__ out) {
    __shared__ float xs[64][132];
    int tid = threadIdx.x;
    int tx = tid & 31;          // col group: cols 4*tx..4*tx+3
    int ty = tid >> 5;          // row group: rows ty*8..ty*8+7
    int row0 = blockIdx.x * 64;
#pragma unroll
    for (int i = 0; i < 8; i++) {
        int idx4 = i * 256 + tid;               // 0..2047 float4 slots
        int r = idx4 >> 5;
        int k4 = (idx4 & 31) * 4;
        int gr = row0 + r;
        float4 vv = (gr < NN) ? *(const float4*)&xin[gr * HH + k4]
                              : make_float4(0.f, 0.f, 0.f, 0.f);
        *(float4*)&xs[r][k4] = vv;
    }
    __syncthreads();
    float acc[8][4];
#pragma unroll
    for (int i = 0; i < 8; i++)
#pragma unroll
        for (int j = 0; j < 4; j++) acc[i][j] = 0.f;

    const float* Wp = W + tx * 4;
#pragma unroll 4
    for (int k = 0; k < 128; k++) {
        float4 w = *(const float4*)&Wp[k * HH];
#pragma unroll
        for (int i = 0; i < 8; i++) {
            float xv = xs[ty * 8 + i][k];
            acc[i][0] += xv * w.x;
            acc[i][1] += xv * w.y;
            acc[i][2] += xv * w.z;
            acc[i][3] += xv * w.w;
        }
    }
#pragma unroll
    for (int i = 0; i < 8; i++) {
        int gr = row0 + ty * 8 + i;
        if (gr < NN)
            *(float4*)&out[gr * HH + tx * 4] =
                make_float4(acc[i][0], acc[i][1], acc[i][2], acc[i][3]);
    }
}

// ---------------- gather-aggregate + bias + BN + ReLU ----------------
// two nodes per wave: half-wave (32 lanes) per node, lane holds 4 channels
// (float4 = 16B, 32 lanes x 16B = full 512B row per half -> 1KB per wave instr).
// edge meta (packed src+wgt) loaded coalesced, broadcast via width-32 shfl.

__global__ __launch_bounds__(256) void k_agg(const float* __restrict__ t,
                                             const int* __restrict__ offs,
                                             const int* __restrict__ cnt,
                                             const int2* __restrict__ meta,
                                             const float* __restrict__ dinv,
                                             const float* __restrict__ bias,
                                             const float* __restrict__ g,
                                             const float* __restrict__ bb,
                                             const float* __restrict__ m,
                                             const float* __restrict__ v,
                                             float* __restrict__ out) {
    int wave = threadIdx.x >> 6;
    int lane = threadIdx.x & 63;
    int half = lane >> 5;
    int l = lane & 31;
    int d = blockIdx.x * 8 + wave * 2 + half;    // NN % 8 == 0
    int c0 = l * 4;
    float dv = dinv[d];
    float w0 = dv * dv;
    float4 self = *(const float4*)&t[d * HH + c0];
    float4 acc;
    acc.x = self.x * w0; acc.y = self.y * w0;
    acc.z = self.z * w0; acc.w = self.w * w0;
    int base = offs[d], cn = cnt[d];
    for (int ib = 0; ib < cn; ib += 32) {
        int i = ib + l;
        int s = 0;
        float w = 0.f;
        if (i < cn) {
            int2 pk = meta[base + i];
            s = pk.x;
            w = __int_as_float(pk.y);
        }
        int lim = min(32, cn - ib);
#pragma unroll 4
        for (int j = 0; j < lim; j++) {
            int ss = __shfl(s, j, 32);
            float ww = __shfl(w, j, 32);
            float4 tv = *(const float4*)&t[ss * HH + c0];
            acc.x += ww * tv.x;
            acc.y += ww * tv.y;
            acc.z += ww * tv.z;
            acc.w += ww * tv.w;
        }
    }
    float4 gg = *(const float4*)&g[c0];
    float4 vv = *(const float4*)&v[c0];
    float4 mm = *(const float4*)&m[c0];
    float4 bv = *(const float4*)&bb[c0];
    float4 bi = *(const float4*)&bias[c0];
    float sc0 = gg.x * rsqrtf(vv.x + BN_EPS);
    float sc1 = gg.y * rsqrtf(vv.y + BN_EPS);
    float sc2 = gg.z * rsqrtf(vv.z + BN_EPS);
    float sc3 = gg.w * rsqrtf(vv.w + BN_EPS);
    float4 o;
    o.x = fmaxf(acc.x * sc0 + (bi.x - mm.x) * sc0 + bv.x, 0.f);
    o.y = fmaxf(acc.y * sc1 + (bi.y - mm.y) * sc1 + bv.y, 0.f);
    o.z = fmaxf(acc.z * sc2 + (bi.z - mm.z) * sc2 + bv.z, 0.f);
    o.w = fmaxf(acc.w * sc3 + (bi.w - mm.w) * sc3 + bv.w, 0.f);
    *(float4*)&out[d * HH + c0] = o;
}

// ---------------- mean pool (batch sorted -> flush on graph change) ----------------

#define PBLK 2048
__global__ void k_pool(const float* __restrict__ h, const int* __restrict__ batch,
                       float* __restrict__ gsum, int* __restrict__ gcnt) {
    int c = threadIdx.x;  // 128
    int per = (NN + PBLK - 1) / PBLK;
    int n0 = blockIdx.x * per;
    int n1 = min(NN, n0 + per);
    if (n0 >= NN) return;
    float acc = 0.f;
    int cur = batch[n0];
    int count = 0;
    for (int n = n0; n < n1; n++) {
        int gr = batch[n];
        if (gr != cur) {
            atomicAdd(&gsum[cur * HH + c], acc);
            if (c == 0) atomicAdd(&gcnt[cur], count);
            acc = 0.f; count = 0; cur = gr;
        }
        acc += h[n * HH + c];
        count++;
    }
    atomicAdd(&gsum[cur * HH + c], acc);
    if (c == 0) atomicAdd(&gcnt[cur], count);
}

__global__ void k_head(const float* __restrict__ gsum, const int* __restrict__ gcnt,
                       const float* __restrict__ linW, const float* __restrict__ linb,
                       float* __restrict__ out) {
    int t = threadIdx.x;        // 128 = 64 graphs x 2 outputs
    int gr = t >> 1, j = t & 1;
    float inv = 1.0f / fmaxf((float)gcnt[gr], 1.0f);
    float acc = 0.f;
    for (int c = 0; c < HH; c++) acc += gsum[gr * HH + c] * linW[c * 2 + j];
    out[t] = acc * inv + linb[j];
}

// ---------------- host launch ----------------

static inline size_t al256(size_t x) { return (x + 255) & ~(size_t)255; }

extern "C" void kernel_launch(void* const* d_in, const int* in_sizes, int n_in,
                              void* d_out, int out_size, void* d_ws, size_t ws_size,
                              hipStream_t stream) {
    const float* x    = (const float*)d_in[0];
    const int*   ei   = (const int*)d_in[1];
    const int*   batch= (const int*)d_in[2];
    const float* W1   = (const float*)d_in[3];
    const float* b1   = (const float*)d_in[4];
    const float* W2   = (const float*)d_in[5];
    const float* b2   = (const float*)d_in[6];
    const float* W3   = (const float*)d_in[7];
    const float* b3   = (const float*)d_in[8];
    const float* linW = (const float*)d_in[9];
    const float* linb = (const float*)d_in[10];
    const float* bn1g = (const float*)d_in[11];
    const float* bn1b = (const float*)d_in[12];
    const float* bn1m = (const float*)d_in[13];
    const float* bn1v = (const float*)d_in[14];
    const float* bn2g = (const float*)d_in[15];
    const float* bn2b = (const float*)d_in[16];
    const float* bn2m = (const float*)d_in[17];
    const float* bn2v = (const float*)d_in[18];
    const float* bn3g = (const float*)d_in[19];
    const float* bn3b = (const float*)d_in[20];
    const float* bn3m = (const float*)d_in[21];
    const float* bn3v = (const float*)d_in[22];
    float* out = (float*)d_out;

    char* ws = (char*)d_ws;
    size_t off = 0;
    int*    cnt    = (int*)(ws + off);    off += al256((size_t)NN * 4);
    int*    cursor = (int*)(ws + off);    off += al256((size_t)NN * 4);
    int*    offs   = (int*)(ws + off);    off += al256((size_t)NN * 4);
    int*    bsum   = (int*)(ws + off);    off += al256(128 * 4);
    float*  dinv   = (float*)(ws + off);  off += al256((size_t)NN * 4);
    int2*   meta   = (int2*)(ws + off);   off += al256((size_t)EE * 8);
    float4* agg    = (float4*)(ws + off); off += al256((size_t)NN * 16);
    float*  bufA   = (float*)(ws + off);  off += al256((size_t)NN * HH * 4);
    float*  bufB   = (float*)(ws + off);  off += al256((size_t)NN * HH * 4);
    float*  gsum   = (float*)(ws + off);  off += (size_t)GG * HH * 4;
    int*    gcnt   = (int*)(ws + off);    off += al256((size_t)GG * 4);

    hipMemsetAsync(cnt, 0, (size_t)NN * 4, stream);
    hipMemsetAsync(cursor, 0, (size_t)NN * 4, stream);
    hipMemsetAsync(agg, 0, (size_t)NN * 16, stream);
    hipMemsetAsync(gsum, 0, (size_t)GG * HH * 4 + (size_t)GG * 4, stream);

    int nblkE = (EE + 255) / 256;
    int nblkN = (NN + 255) / 256;
    int nblkScan = (NN + 1023) / 1024;   // 98

    k_count<<<nblkE, 256, 0, stream>>>(ei, cnt);
    k_dinv<<<nblkN, 256, 0, stream>>>(cnt, dinv);
    k_scan1<<<nblkScan, 256, 0, stream>>>(cnt, offs, bsum);
    k_scan2<<<1, 128, 0, stream>>>(bsum, nblkScan);
    k_scan3<<<nblkN, 256, 0, stream>>>(offs, bsum);
    k_bucket<<<nblkE, 256, 0, stream>>>(ei, offs, cursor, dinv, x, meta, agg);

    // layer 1: fused 4x128 matmul + BN + ReLU -> bufA
    k_l1<<<(NN + L1R - 1) / L1R, 128, 0, stream>>>(agg, x, dinv, W1, b1,
                                                   bn1g, bn1b, bn1m, bn1v, bufA);

    // layer 2: t = bufA @ W2 -> bufB ; aggregate + bias + BN + ReLU -> bufA
    k_mm<<<(NN + 63) / 64, 256, 0, stream>>>(bufA, W2, bufB);
    k_agg<<<NN / 8, 256, 0, stream>>>(bufB, offs, cnt, meta, dinv,
                                      b2, bn2g, bn2b, bn2m, bn2v, bufA);

    // layer 3
    k_mm<<<(NN + 63) / 64, 256, 0, stream>>>(bufA, W3, bufB);
    k_agg<<<NN / 8, 256, 0, stream>>>(bufB, offs, cnt, meta, dinv,
                                      b3, bn3g, bn3b, bn3m, bn3v, bufA);

    // pool + head
    k_pool<<<PBLK, 128, 0, stream>>>(bufA, batch, gsum, gcnt);
    k_head<<<1, 128, 0, stream>>>(gsum, gcnt, linW, linb, out);
}

// Round 3
// 564.559 us; speedup vs baseline: 1.5428x; 1.5428x over previous
//
#include <hip/hip_runtime.h>

#define NN 100000
#define EE 1600000
#define GG 64
#define HH 128
#define BN_EPS 1e-5f

#define CB 782            // coarse buckets = ceil(NN/128), bucket = dst>>7
#define NB 512            // tiles for hist/scatter passes
#define TILE 3125         // EE / NB exactly

// ---------------- graph prep: atomic-free two-level counting sort ----------------

// pass A: per-tile coarse histogram (LDS only)
__global__ __launch_bounds__(256) void k_hist(const int* __restrict__ ei,
                                              int* __restrict__ histG) {
    __shared__ int h[CB];
    int t = threadIdx.x;
    for (int i = t; i < CB; i += 256) h[i] = 0;
    __syncthreads();
    int e0 = blockIdx.x * TILE;
    for (int i = t; i < TILE; i += 256) {
        int d = ei[EE + e0 + i];
        atomicAdd(&h[d >> 7], 1);
    }
    __syncthreads();
    for (int i = t; i < CB; i += 256) histG[blockIdx.x * CB + i] = h[i];
}

// pass B: for each coarse bucket c, exclusive-scan histG[:,c] over the 512 tiles
__global__ __launch_bounds__(512) void k_bscan(int* __restrict__ histG,
                                               int* __restrict__ total) {
    __shared__ int sh[NB];
    int t = threadIdx.x;
    int c = blockIdx.x;
    sh[t] = histG[t * CB + c];
    __syncthreads();
    for (int d = 1; d < NB; d <<= 1) {
        int x = (t >= d) ? sh[t - d] : 0;
        __syncthreads();
        sh[t] += x;
        __syncthreads();
    }
    histG[t * CB + c] = (t > 0) ? sh[t - 1] : 0;
    if (t == NB - 1) total[c] = sh[NB - 1];
}

// pass B2: scan bucket totals -> coarse bases
__global__ __launch_bounds__(1024) void k_cbase(const int* __restrict__ total,
                                                int* __restrict__ cbase) {
    __shared__ int sh[1024];
    int t = threadIdx.x;
    sh[t] = (t < CB) ? total[t] : 0;
    __syncthreads();
    for (int d = 1; d < 1024; d <<= 1) {
        int x = (t >= d) ? sh[t - d] : 0;
        __syncthreads();
        sh[t] += x;
        __syncthreads();
    }
    if (t < CB) cbase[t] = (t > 0) ? sh[t - 1] : 0;
    if (t == CB - 1) cbase[CB] = sh[t];   // == EE
}

// pass C: scatter edges into coarse-sorted order; payload = src | (dst&127)<<17
__global__ __launch_bounds__(256) void k_cscatter(const int* __restrict__ ei,
                                                  const int* __restrict__ histG,
                                                  const int* __restrict__ cbase,
                                                  int* __restrict__ metaS) {
    __shared__ int base_l[CB];
    __shared__ int cur_l[CB];
    int t = threadIdx.x;
    int b = blockIdx.x;
    for (int i = t; i < CB; i += 256) {
        base_l[i] = cbase[i] + histG[b * CB + i];
        cur_l[i] = 0;
    }
    __syncthreads();
    int e0 = b * TILE;
    for (int i = t; i < TILE; i += 256) {
        int s = ei[e0 + i];
        int d = ei[EE + e0 + i];
        int c = d >> 7;
        int p = base_l[c] + atomicAdd(&cur_l[c], 1);
        metaS[p] = s | ((d & 127) << 17);
    }
}

// pass D: one block per coarse bucket -> fine histogram, cnt/offs, sorted col
__global__ __launch_bounds__(256) void k_fine(const int* __restrict__ metaS,
                                              const int* __restrict__ cbase,
                                              int* __restrict__ cnt,
                                              int* __restrict__ offs,
                                              int* __restrict__ col) {
    __shared__ int hist[128];
    __shared__ int scn[128];
    __shared__ int cur[128];
    int t = threadIdx.x;
    int c = blockIdx.x;
    int lo = cbase[c], hi = cbase[c + 1];
    if (t < 128) hist[t] = 0;
    __syncthreads();
    for (int r = lo + t; r < hi; r += 256) atomicAdd(&hist[metaS[r] >> 17], 1);
    __syncthreads();
    if (t < 128) scn[t] = hist[t];
    __syncthreads();
    for (int d = 1; d < 128; d <<= 1) {
        int x = (t >= d && t < 128) ? scn[t - d] : 0;
        __syncthreads();
        if (t < 128) scn[t] += x;
        __syncthreads();
    }
    if (t < 128) {
        int excl = (t > 0) ? scn[t - 1] : 0;
        cur[t] = excl;
        int node = c * 128 + t;
        if (node < NN) {
            cnt[node] = hist[t];
            offs[node] = lo + excl;
        }
    }
    __syncthreads();
    for (int r = lo + t; r < hi; r += 256) {
        int pk = metaS[r];
        int s = pk & 0x1FFFF;
        int idx = atomicAdd(&cur[pk >> 17], 1);
        col[lo + idx] = s;
    }
}

__global__ void k_dinv(const int* __restrict__ cnt, float* __restrict__ dinv) {
    int n = blockIdx.x * blockDim.x + threadIdx.x;
    if (n < NN) dinv[n] = rsqrtf((float)(cnt[n] + 1));   // +1 self loop
}

// ---------------- layer 1 aggregate (3-dim, CSR gather) + weight materialize ----------------

__global__ void k_aggx(const float* __restrict__ x, const int* __restrict__ offs,
                       const int* __restrict__ cnt, const int* __restrict__ col,
                       const float* __restrict__ dinv, float* __restrict__ wgt,
                       float4* __restrict__ agg) {
    int n = blockIdx.x * blockDim.x + threadIdx.x;
    if (n >= NN) return;
    float dv = dinv[n];
    float w0 = dv * dv;
    float a0 = x[n * 3 + 0] * w0;
    float a1 = x[n * 3 + 1] * w0;
    float a2 = x[n * 3 + 2] * w0;
    int base = offs[n], c = cnt[n];
    for (int i = 0; i < c; i++) {
        int s = col[base + i];
        float w = dinv[s] * dv;
        wgt[base + i] = w;
        a0 += w * x[s * 3 + 0];
        a1 += w * x[s * 3 + 1];
        a2 += w * x[s * 3 + 2];
    }
    agg[n] = make_float4(a0, a1, a2, 0.f);
}

// ---------------- layer 1: agg @ W1 + bias + BN + ReLU ----------------

#define L1R 16
__global__ void k_l1(const float4* __restrict__ agg,
                     const float* __restrict__ W1,
                     const float* __restrict__ b1, const float* __restrict__ g,
                     const float* __restrict__ bb, const float* __restrict__ m,
                     const float* __restrict__ v, float* __restrict__ out) {
    int c = threadIdx.x;                       // 0..127
    float w0 = W1[c], w1 = W1[128 + c], w2 = W1[256 + c];
    float sc = g[c] * rsqrtf(v[c] + BN_EPS);
    float sh = (b1[c] - m[c]) * sc + bb[c];
    int r0 = blockIdx.x * L1R;
    for (int i = 0; i < L1R; i++) {
        int n = r0 + i;
        if (n >= NN) break;
        float4 a = agg[n];
        float t = a.x * w0 + a.y * w1 + a.z * w2;
        t = t * sc + sh;
        out[n * HH + c] = fmaxf(t, 0.f);
    }
}

// ---------------- dense 128x128 matmul (fp32 vector) ----------------

__global__ __launch_bounds__(256) void k_mm(const float* __restrict__ xin,
                                            const float* __restrict__ W,
                                            float* __restrict__ out) {
    __shared__ float xs[64][132];
    int tid = threadIdx.x;
    int tx = tid & 31;
    int ty = tid >> 5;
    int row0 = blockIdx.x * 64;
#pragma unroll
    for (int i = 0; i < 8; i++) {
        int idx4 = i * 256 + tid;
        int r = idx4 >> 5;
        int k4 = (idx4 & 31) * 4;
        int gr = row0 + r;
        float4 vv = (gr < NN) ? *(const float4*)&xin[gr * HH + k4]
                              : make_float4(0.f, 0.f, 0.f, 0.f);
        *(float4*)&xs[r][k4] = vv;
    }
    __syncthreads();
    float acc[8][4];
#pragma unroll
    for (int i = 0; i < 8; i++)
#pragma unroll
        for (int j = 0; j < 4; j++) acc[i][j] = 0.f;

    const float* Wp = W + tx * 4;
#pragma unroll 4
    for (int k = 0; k < 128; k++) {
        float4 w = *(const float4*)&Wp[k * HH];
#pragma unroll
        for (int i = 0; i < 8; i++) {
            float xv = xs[ty * 8 + i][k];
            acc[i][0] += xv * w.x;
            acc[i][1] += xv * w.y;
            acc[i][2] += xv * w.z;
            acc[i][3] += xv * w.w;
        }
    }
#pragma unroll
    for (int i = 0; i < 8; i++) {
        int gr = row0 + ty * 8 + i;
        if (gr < NN)
            *(float4*)&out[gr * HH + tx * 4] =
                make_float4(acc[i][0], acc[i][1], acc[i][2], acc[i][3]);
    }
}

// ---------------- gather-aggregate + bias + BN + ReLU ----------------
// half-wave (32 lanes) per node, lane holds float4 (full 512B row per half)

__global__ __launch_bounds__(256) void k_agg(const float* __restrict__ t,
                                             const int* __restrict__ offs,
                                             const int* __restrict__ cnt,
                                             const int* __restrict__ col,
                                             const float* __restrict__ wgt,
                                             const float* __restrict__ dinv,
                                             const float* __restrict__ bias,
                                             const float* __restrict__ g,
                                             const float* __restrict__ bb,
                                             const float* __restrict__ m,
                                             const float* __restrict__ v,
                                             float* __restrict__ out) {
    int wave = threadIdx.x >> 6;
    int lane = threadIdx.x & 63;
    int half = lane >> 5;
    int l = lane & 31;
    int d = blockIdx.x * 8 + wave * 2 + half;    // NN % 8 == 0
    int c0 = l * 4;
    float dv = dinv[d];
    float w0 = dv * dv;
    float4 self = *(const float4*)&t[d * HH + c0];
    float4 acc;
    acc.x = self.x * w0; acc.y = self.y * w0;
    acc.z = self.z * w0; acc.w = self.w * w0;
    int base = offs[d], cn = cnt[d];
    for (int ib = 0; ib < cn; ib += 32) {
        int i = ib + l;
        int s = 0;
        float w = 0.f;
        if (i < cn) {
            s = col[base + i];
            w = wgt[base + i];
        }
        int lim = min(32, cn - ib);
#pragma unroll 4
        for (int j = 0; j < lim; j++) {
            int ss = __shfl(s, j, 32);
            float ww = __shfl(w, j, 32);
            float4 tv = *(const float4*)&t[ss * HH + c0];
            acc.x += ww * tv.x;
            acc.y += ww * tv.y;
            acc.z += ww * tv.z;
            acc.w += ww * tv.w;
        }
    }
    float4 gg = *(const float4*)&g[c0];
    float4 vv = *(const float4*)&v[c0];
    float4 mm = *(const float4*)&m[c0];
    float4 bv = *(const float4*)&bb[c0];
    float4 bi = *(const float4*)&bias[c0];
    float sc0 = gg.x * rsqrtf(vv.x + BN_EPS);
    float sc1 = gg.y * rsqrtf(vv.y + BN_EPS);
    float sc2 = gg.z * rsqrtf(vv.z + BN_EPS);
    float sc3 = gg.w * rsqrtf(vv.w + BN_EPS);
    float4 o;
    o.x = fmaxf(acc.x * sc0 + (bi.x - mm.x) * sc0 + bv.x, 0.f);
    o.y = fmaxf(acc.y * sc1 + (bi.y - mm.y) * sc1 + bv.y, 0.f);
    o.z = fmaxf(acc.z * sc2 + (bi.z - mm.z) * sc2 + bv.z, 0.f);
    o.w = fmaxf(acc.w * sc3 + (bi.w - mm.w) * sc3 + bv.w, 0.f);
    *(float4*)&out[d * HH + c0] = o;
}

// ---------------- mean pool (batch sorted -> flush on graph change) ----------------

#define PBLK 2048
__global__ void k_pool(const float* __restrict__ h, const int* __restrict__ batch,
                       float* __restrict__ gsum, int* __restrict__ gcnt) {
    int c = threadIdx.x;  // 128
    int per = (NN + PBLK - 1) / PBLK;
    int n0 = blockIdx.x * per;
    int n1 = min(NN, n0 + per);
    if (n0 >= NN) return;
    float acc = 0.f;
    int cur = batch[n0];
    int count = 0;
    for (int n = n0; n < n1; n++) {
        int gr = batch[n];
        if (gr != cur) {
            atomicAdd(&gsum[cur * HH + c], acc);
            if (c == 0) atomicAdd(&gcnt[cur], count);
            acc = 0.f; count = 0; cur = gr;
        }
        acc += h[n * HH + c];
        count++;
    }
    atomicAdd(&gsum[cur * HH + c], acc);
    if (c == 0) atomicAdd(&gcnt[cur], count);
}

__global__ void k_head(const float* __restrict__ gsum, const int* __restrict__ gcnt,
                       const float* __restrict__ linW, const float* __restrict__ linb,
                       float* __restrict__ out) {
    int t = threadIdx.x;        // 128 = 64 graphs x 2 outputs
    int gr = t >> 1, j = t & 1;
    float inv = 1.0f / fmaxf((float)gcnt[gr], 1.0f);
    float acc = 0.f;
    for (int c = 0; c < HH; c++) acc += gsum[gr * HH + c] * linW[c * 2 + j];
    out[t] = acc * inv + linb[j];
}

// ---------------- host launch ----------------

static inline size_t al256(size_t x) { return (x + 255) & ~(size_t)255; }

extern "C" void kernel_launch(void* const* d_in, const int* in_sizes, int n_in,
                              void* d_out, int out_size, void* d_ws, size_t ws_size,
                              hipStream_t stream) {
    const float* x    = (const float*)d_in[0];
    const int*   ei   = (const int*)d_in[1];
    const int*   batch= (const int*)d_in[2];
    const float* W1   = (const float*)d_in[3];
    const float* b1   = (const float*)d_in[4];
    const float* W2   = (const float*)d_in[5];
    const float* b2   = (const float*)d_in[6];
    const float* W3   = (const float*)d_in[7];
    const float* b3   = (const float*)d_in[8];
    const float* linW = (const float*)d_in[9];
    const float* linb = (const float*)d_in[10];
    const float* bn1g = (const float*)d_in[11];
    const float* bn1b = (const float*)d_in[12];
    const float* bn1m = (const float*)d_in[13];
    const float* bn1v = (const float*)d_in[14];
    const float* bn2g = (const float*)d_in[15];
    const float* bn2b = (const float*)d_in[16];
    const float* bn2m = (const float*)d_in[17];
    const float* bn2v = (const float*)d_in[18];
    const float* bn3g = (const float*)d_in[19];
    const float* bn3b = (const float*)d_in[20];
    const float* bn3m = (const float*)d_in[21];
    const float* bn3v = (const float*)d_in[22];
    float* out = (float*)d_out;

    char* ws = (char*)d_ws;
    size_t off = 0;
    int*    histG  = (int*)(ws + off);    off += al256((size_t)NB * CB * 4);
    int*    total  = (int*)(ws + off);    off += al256((size_t)CB * 4);
    int*    cbase  = (int*)(ws + off);    off += al256((size_t)(CB + 1) * 4);
    int*    cnt    = (int*)(ws + off);    off += al256((size_t)NN * 4);
    int*    offs   = (int*)(ws + off);    off += al256((size_t)NN * 4);
    float*  dinv   = (float*)(ws + off);  off += al256((size_t)NN * 4);
    int*    col    = (int*)(ws + off);    off += al256((size_t)EE * 4);
    float*  wgt    = (float*)(ws + off);  off += al256((size_t)EE * 4);
    float4* agg    = (float4*)(ws + off); off += al256((size_t)NN * 16);
    float*  bufA   = (float*)(ws + off);  off += al256((size_t)NN * HH * 4);
    float*  bufB   = (float*)(ws + off);  off += al256((size_t)NN * HH * 4);
    float*  gsum   = (float*)(ws + off);  off += (size_t)GG * HH * 4;
    int*    gcnt   = (int*)(ws + off);    off += al256((size_t)GG * 4);

    // metaS (coarse-sorted packed edges, 6.4MB) overlays bufB: it is fully
    // consumed by k_fine before bufB's first write (k_mm layer 2).
    int* metaS = (int*)bufB;

    hipMemsetAsync(gsum, 0, (size_t)GG * HH * 4 + (size_t)GG * 4, stream);

    int nblkN = (NN + 255) / 256;

    // atomic-free counting sort -> CSR
    k_hist<<<NB, 256, 0, stream>>>(ei, histG);
    k_bscan<<<CB, NB, 0, stream>>>(histG, total);
    k_cbase<<<1, 1024, 0, stream>>>(total, cbase);
    k_cscatter<<<NB, 256, 0, stream>>>(ei, histG, cbase, metaS);
    k_fine<<<CB, 256, 0, stream>>>(metaS, cbase, cnt, offs, col);
    k_dinv<<<nblkN, 256, 0, stream>>>(cnt, dinv);

    // layer 1: aggregate in input space (3-dim) + materialize weights, then fused matmul
    k_aggx<<<nblkN, 256, 0, stream>>>(x, offs, cnt, col, dinv, wgt, agg);
    k_l1<<<(NN + L1R - 1) / L1R, 128, 0, stream>>>(agg, W1, b1, bn1g, bn1b, bn1m, bn1v, bufA);

    // layer 2
    k_mm<<<(NN + 63) / 64, 256, 0, stream>>>(bufA, W2, bufB);
    k_agg<<<NN / 8, 256, 0, stream>>>(bufB, offs, cnt, col, wgt, dinv,
                                      b2, bn2g, bn2b, bn2m, bn2v, bufA);

    // layer 3
    k_mm<<<(NN + 63) / 64, 256, 0, stream>>>(bufA, W3, bufB);
    k_agg<<<NN / 8, 256, 0, stream>>>(bufB, offs, cnt, col, wgt, dinv,
                                      b3, bn3g, bn3b, bn3m, bn3v, bufA);

    // pool + head
    k_pool<<<PBLK, 128, 0, stream>>>(bufA, batch, gsum, gcnt);
    k_head<<<1, 128, 0, stream>>>(gsum, gcnt, linW, linb, out);
}

// Round 4
// 460.584 us; speedup vs baseline: 1.8910x; 1.2257x over previous
//
#include <hip/hip_runtime.h>

#define NN 100000
#define EE 1600000
#define GG 64
#define HH 128
#define BN_EPS 1e-5f

#define CB 782            // coarse buckets = ceil(NN/128), bucket = dst>>7
#define NB 512            // tiles for hist/scatter passes
#define TILE 3125         // EE / NB exactly

typedef unsigned short ushort_t;

// round-to-nearest-even fp32 -> bf16 (finite values)
static __device__ inline ushort_t f2bf(float f) {
    unsigned u = __float_as_uint(f);
    unsigned r = (u + 0x7FFF + ((u >> 16) & 1)) >> 16;
    return (ushort_t)r;
}
static __device__ inline float bf2f(ushort_t b) {
    return __uint_as_float(((unsigned)b) << 16);
}

// ---------------- graph prep: atomic-free two-level counting sort ----------------

__global__ __launch_bounds__(256) void k_hist(const int* __restrict__ ei,
                                              int* __restrict__ histG) {
    __shared__ int h[CB];
    int t = threadIdx.x;
    for (int i = t; i < CB; i += 256) h[i] = 0;
    __syncthreads();
    int e0 = blockIdx.x * TILE;
    for (int i = t; i < TILE; i += 256) {
        int d = ei[EE + e0 + i];
        atomicAdd(&h[d >> 7], 1);
    }
    __syncthreads();
    for (int i = t; i < CB; i += 256) histG[blockIdx.x * CB + i] = h[i];
}

__global__ __launch_bounds__(512) void k_bscan(int* __restrict__ histG,
                                               int* __restrict__ total) {
    __shared__ int sh[NB];
    int t = threadIdx.x;
    int c = blockIdx.x;
    sh[t] = histG[t * CB + c];
    __syncthreads();
    for (int d = 1; d < NB; d <<= 1) {
        int x = (t >= d) ? sh[t - d] : 0;
        __syncthreads();
        sh[t] += x;
        __syncthreads();
    }
    histG[t * CB + c] = (t > 0) ? sh[t - 1] : 0;
    if (t == NB - 1) total[c] = sh[NB - 1];
}

__global__ __launch_bounds__(1024) void k_cbase(const int* __restrict__ total,
                                                int* __restrict__ cbase) {
    __shared__ int sh[1024];
    int t = threadIdx.x;
    sh[t] = (t < CB) ? total[t] : 0;
    __syncthreads();
    for (int d = 1; d < 1024; d <<= 1) {
        int x = (t >= d) ? sh[t - d] : 0;
        __syncthreads();
        sh[t] += x;
        __syncthreads();
    }
    if (t < CB) cbase[t] = (t > 0) ? sh[t - 1] : 0;
    if (t == CB - 1) cbase[CB] = sh[t];   // == EE
}

__global__ __launch_bounds__(256) void k_cscatter(const int* __restrict__ ei,
                                                  const int* __restrict__ histG,
                                                  const int* __restrict__ cbase,
                                                  int* __restrict__ metaS) {
    __shared__ int base_l[CB];
    __shared__ int cur_l[CB];
    int t = threadIdx.x;
    int b = blockIdx.x;
    for (int i = t; i < CB; i += 256) {
        base_l[i] = cbase[i] + histG[b * CB + i];
        cur_l[i] = 0;
    }
    __syncthreads();
    int e0 = b * TILE;
    for (int i = t; i < TILE; i += 256) {
        int s = ei[e0 + i];
        int d = ei[EE + e0 + i];
        int c = d >> 7;
        int p = base_l[c] + atomicAdd(&cur_l[c], 1);
        metaS[p] = s | ((d & 127) << 17);
    }
}

__global__ __launch_bounds__(256) void k_fine(const int* __restrict__ metaS,
                                              const int* __restrict__ cbase,
                                              int* __restrict__ cnt,
                                              int* __restrict__ offs,
                                              int* __restrict__ col) {
    __shared__ int hist[128];
    __shared__ int scn[128];
    __shared__ int cur[128];
    int t = threadIdx.x;
    int c = blockIdx.x;
    int lo = cbase[c], hi = cbase[c + 1];
    if (t < 128) hist[t] = 0;
    __syncthreads();
    for (int r = lo + t; r < hi; r += 256) atomicAdd(&hist[metaS[r] >> 17], 1);
    __syncthreads();
    if (t < 128) scn[t] = hist[t];
    __syncthreads();
    for (int d = 1; d < 128; d <<= 1) {
        int x = (t >= d && t < 128) ? scn[t - d] : 0;
        __syncthreads();
        if (t < 128) scn[t] += x;
        __syncthreads();
    }
    if (t < 128) {
        int excl = (t > 0) ? scn[t - 1] : 0;
        cur[t] = excl;
        int node = c * 128 + t;
        if (node < NN) {
            cnt[node] = hist[t];
            offs[node] = lo + excl;
        }
    }
    __syncthreads();
    for (int r = lo + t; r < hi; r += 256) {
        int pk = metaS[r];
        int s = pk & 0x1FFFF;
        int idx = atomicAdd(&cur[pk >> 17], 1);
        col[lo + idx] = s;
    }
}

__global__ void k_dinv(const int* __restrict__ cnt, float* __restrict__ dinv) {
    int n = blockIdx.x * blockDim.x + threadIdx.x;
    if (n < NN) dinv[n] = rsqrtf((float)(cnt[n] + 1));   // +1 self loop
}

// ---------------- layer 1 aggregate (3-dim) + weight materialize ----------------
// 16-lane group per node: lane-parallel edges, shfl-xor reduction

__global__ __launch_bounds__(256) void k_aggx(const float* __restrict__ x,
                                              const int* __restrict__ offs,
                                              const int* __restrict__ cnt,
                                              const int* __restrict__ col,
                                              const float* __restrict__ dinv,
                                              float* __restrict__ wgt,
                                              float4* __restrict__ agg) {
    int tid = threadIdx.x;
    int wave = tid >> 6;
    int lane = tid & 63;
    int grp = lane >> 4;
    int l = lane & 15;
    int n = blockIdx.x * 16 + wave * 4 + grp;    // NN % 16 == 0
    float dv = dinv[n];
    int base = offs[n], cn = cnt[n];
    float a0 = 0.f, a1 = 0.f, a2 = 0.f;
    for (int i = l; i < cn; i += 16) {
        int s = col[base + i];
        float w = dinv[s] * dv;
        wgt[base + i] = w;
        a0 += w * x[s * 3 + 0];
        a1 += w * x[s * 3 + 1];
        a2 += w * x[s * 3 + 2];
    }
#pragma unroll
    for (int off = 8; off >= 1; off >>= 1) {
        a0 += __shfl_xor(a0, off, 16);
        a1 += __shfl_xor(a1, off, 16);
        a2 += __shfl_xor(a2, off, 16);
    }
    if (l == 0) {
        float w0 = dv * dv;
        a0 += w0 * x[n * 3 + 0];
        a1 += w0 * x[n * 3 + 1];
        a2 += w0 * x[n * 3 + 2];
        agg[n] = make_float4(a0, a1, a2, 0.f);
    }
}

// ---------------- layer 1: agg @ W1 + bias + BN + ReLU ----------------

#define L1R 16
__global__ void k_l1(const float4* __restrict__ agg,
                     const float* __restrict__ W1,
                     const float* __restrict__ b1, const float* __restrict__ g,
                     const float* __restrict__ bb, const float* __restrict__ m,
                     const float* __restrict__ v, float* __restrict__ out) {
    int c = threadIdx.x;                       // 0..127
    float w0 = W1[c], w1 = W1[128 + c], w2 = W1[256 + c];
    float sc = g[c] * rsqrtf(v[c] + BN_EPS);
    float sh = (b1[c] - m[c]) * sc + bb[c];
    int r0 = blockIdx.x * L1R;
    for (int i = 0; i < L1R; i++) {
        int n = r0 + i;
        if (n >= NN) break;
        float4 a = agg[n];
        float t = a.x * w0 + a.y * w1 + a.z * w2;
        t = t * sc + sh;
        out[n * HH + c] = fmaxf(t, 0.f);
    }
}

// ---------------- dense 128x128 matmul, bf16 output ----------------

__global__ __launch_bounds__(256) void k_mm(const float* __restrict__ xin,
                                            const float* __restrict__ W,
                                            ushort_t* __restrict__ outB) {
    __shared__ float xs[64][132];
    int tid = threadIdx.x;
    int tx = tid & 31;
    int ty = tid >> 5;
    int row0 = blockIdx.x * 64;
#pragma unroll
    for (int i = 0; i < 8; i++) {
        int idx4 = i * 256 + tid;
        int r = idx4 >> 5;
        int k4 = (idx4 & 31) * 4;
        int gr = row0 + r;
        float4 vv = (gr < NN) ? *(const float4*)&xin[gr * HH + k4]
                              : make_float4(0.f, 0.f, 0.f, 0.f);
        *(float4*)&xs[r][k4] = vv;
    }
    __syncthreads();
    float acc[8][4];
#pragma unroll
    for (int i = 0; i < 8; i++)
#pragma unroll
        for (int j = 0; j < 4; j++) acc[i][j] = 0.f;

    const float* Wp = W + tx * 4;
#pragma unroll 4
    for (int k = 0; k < 128; k++) {
        float4 w = *(const float4*)&Wp[k * HH];
#pragma unroll
        for (int i = 0; i < 8; i++) {
            float xv = xs[ty * 8 + i][k];
            acc[i][0] += xv * w.x;
            acc[i][1] += xv * w.y;
            acc[i][2] += xv * w.z;
            acc[i][3] += xv * w.w;
        }
    }
#pragma unroll
    for (int i = 0; i < 8; i++) {
        int gr = row0 + ty * 8 + i;
        if (gr < NN) {
            ushort4 o;
            o.x = f2bf(acc[i][0]);
            o.y = f2bf(acc[i][1]);
            o.z = f2bf(acc[i][2]);
            o.w = f2bf(acc[i][3]);
            *(ushort4*)&outB[(size_t)gr * HH + tx * 4] = o;
        }
    }
}

// ---------------- gather-aggregate (bf16 rows) + bias + BN + ReLU ----------------
// half-wave (32 lanes) per node, lane holds 4 bf16 channels (8B), fp32 accum

__global__ __launch_bounds__(256) void k_agg(const ushort_t* __restrict__ t,
                                             const int* __restrict__ offs,
                                             const int* __restrict__ cnt,
                                             const int* __restrict__ col,
                                             const float* __restrict__ wgt,
                                             const float* __restrict__ dinv,
                                             const float* __restrict__ bias,
                                             const float* __restrict__ g,
                                             const float* __restrict__ bb,
                                             const float* __restrict__ m,
                                             const float* __restrict__ v,
                                             float* __restrict__ out) {
    int wave = threadIdx.x >> 6;
    int lane = threadIdx.x & 63;
    int half = lane >> 5;
    int l = lane & 31;
    int d = blockIdx.x * 8 + wave * 2 + half;    // NN % 8 == 0
    int c0 = l * 4;
    float dv = dinv[d];
    float w0 = dv * dv;
    ushort4 selfR = *(const ushort4*)&t[(size_t)d * HH + c0];
    float4 acc;
    acc.x = bf2f(selfR.x) * w0; acc.y = bf2f(selfR.y) * w0;
    acc.z = bf2f(selfR.z) * w0; acc.w = bf2f(selfR.w) * w0;
    int base = offs[d], cn = cnt[d];
    for (int ib = 0; ib < cn; ib += 32) {
        int i = ib + l;
        int s = 0;
        float w = 0.f;
        if (i < cn) {
            s = col[base + i];
            w = wgt[base + i];
        }
        int lim = min(32, cn - ib);
#pragma unroll 4
        for (int j = 0; j < lim; j++) {
            int ss = __shfl(s, j, 32);
            float ww = __shfl(w, j, 32);
            ushort4 tv = *(const ushort4*)&t[(size_t)ss * HH + c0];
            acc.x += ww * bf2f(tv.x);
            acc.y += ww * bf2f(tv.y);
            acc.z += ww * bf2f(tv.z);
            acc.w += ww * bf2f(tv.w);
        }
    }
    float4 gg = *(const float4*)&g[c0];
    float4 vv = *(const float4*)&v[c0];
    float4 mm = *(const float4*)&m[c0];
    float4 bv = *(const float4*)&bb[c0];
    float4 bi = *(const float4*)&bias[c0];
    float sc0 = gg.x * rsqrtf(vv.x + BN_EPS);
    float sc1 = gg.y * rsqrtf(vv.y + BN_EPS);
    float sc2 = gg.z * rsqrtf(vv.z + BN_EPS);
    float sc3 = gg.w * rsqrtf(vv.w + BN_EPS);
    float4 o;
    o.x = fmaxf(acc.x * sc0 + (bi.x - mm.x) * sc0 + bv.x, 0.f);
    o.y = fmaxf(acc.y * sc1 + (bi.y - mm.y) * sc1 + bv.y, 0.f);
    o.z = fmaxf(acc.z * sc2 + (bi.z - mm.z) * sc2 + bv.z, 0.f);
    o.w = fmaxf(acc.w * sc3 + (bi.w - mm.w) * sc3 + bv.w, 0.f);
    *(float4*)&out[d * HH + c0] = o;
}

// ---------------- mean pool ----------------

#define PBLK 2048
__global__ void k_pool(const float* __restrict__ h, const int* __restrict__ batch,
                       float* __restrict__ gsum, int* __restrict__ gcnt) {
    int c = threadIdx.x;  // 128
    int per = (NN + PBLK - 1) / PBLK;
    int n0 = blockIdx.x * per;
    int n1 = min(NN, n0 + per);
    if (n0 >= NN) return;
    float acc = 0.f;
    int cur = batch[n0];
    int count = 0;
    for (int n = n0; n < n1; n++) {
        int gr = batch[n];
        if (gr != cur) {
            atomicAdd(&gsum[cur * HH + c], acc);
            if (c == 0) atomicAdd(&gcnt[cur], count);
            acc = 0.f; count = 0; cur = gr;
        }
        acc += h[n * HH + c];
        count++;
    }
    atomicAdd(&gsum[cur * HH + c], acc);
    if (c == 0) atomicAdd(&gcnt[cur], count);
}

__global__ void k_head(const float* __restrict__ gsum, const int* __restrict__ gcnt,
                       const float* __restrict__ linW, const float* __restrict__ linb,
                       float* __restrict__ out) {
    int t = threadIdx.x;        // 128 = 64 graphs x 2 outputs
    int gr = t >> 1, j = t & 1;
    float inv = 1.0f / fmaxf((float)gcnt[gr], 1.0f);
    float acc = 0.f;
    for (int c = 0; c < HH; c++) acc += gsum[gr * HH + c] * linW[c * 2 + j];
    out[t] = acc * inv + linb[j];
}

// ---------------- host launch ----------------

static inline size_t al256(size_t x) { return (x + 255) & ~(size_t)255; }

extern "C" void kernel_launch(void* const* d_in, const int* in_sizes, int n_in,
                              void* d_out, int out_size, void* d_ws, size_t ws_size,
                              hipStream_t stream) {
    const float* x    = (const float*)d_in[0];
    const int*   ei   = (const int*)d_in[1];
    const int*   batch= (const int*)d_in[2];
    const float* W1   = (const float*)d_in[3];
    const float* b1   = (const float*)d_in[4];
    const float* W2   = (const float*)d_in[5];
    const float* b2   = (const float*)d_in[6];
    const float* W3   = (const float*)d_in[7];
    const float* b3   = (const float*)d_in[8];
    const float* linW = (const float*)d_in[9];
    const float* linb = (const float*)d_in[10];
    const float* bn1g = (const float*)d_in[11];
    const float* bn1b = (const float*)d_in[12];
    const float* bn1m = (const float*)d_in[13];
    const float* bn1v = (const float*)d_in[14];
    const float* bn2g = (const float*)d_in[15];
    const float* bn2b = (const float*)d_in[16];
    const float* bn2m = (const float*)d_in[17];
    const float* bn2v = (const float*)d_in[18];
    const float* bn3g = (const float*)d_in[19];
    const float* bn3b = (const float*)d_in[20];
    const float* bn3m = (const float*)d_in[21];
    const float* bn3v = (const float*)d_in[22];
    float* out = (float*)d_out;

    char* ws = (char*)d_ws;
    size_t off = 0;
    int*    histG  = (int*)(ws + off);    off += al256((size_t)NB * CB * 4);
    int*    total  = (int*)(ws + off);    off += al256((size_t)CB * 4);
    int*    cbase  = (int*)(ws + off);    off += al256((size_t)(CB + 1) * 4);
    int*    cnt    = (int*)(ws + off);    off += al256((size_t)NN * 4);
    int*    offs   = (int*)(ws + off);    off += al256((size_t)NN * 4);
    float*  dinv   = (float*)(ws + off);  off += al256((size_t)NN * 4);
    int*    col    = (int*)(ws + off);    off += al256((size_t)EE * 4);
    float*  wgt    = (float*)(ws + off);  off += al256((size_t)EE * 4);
    float4* agg    = (float4*)(ws + off); off += al256((size_t)NN * 16);
    float*  bufA   = (float*)(ws + off);  off += al256((size_t)NN * HH * 4);
    char*   bufB   = (char*)(ws + off);   off += al256((size_t)NN * HH * 4);
    float*  gsum   = (float*)(ws + off);  off += (size_t)GG * HH * 4;
    int*    gcnt   = (int*)(ws + off);    off += al256((size_t)GG * 4);

    // metaS (coarse-sorted packed edges, 6.4MB) and tB (bf16 t-buffer, 25.6MB)
    // both overlay bufB: metaS fully consumed by k_fine before first k_mm write.
    int* metaS = (int*)bufB;
    ushort_t* tB = (ushort_t*)bufB;

    hipMemsetAsync(gsum, 0, (size_t)GG * HH * 4 + (size_t)GG * 4, stream);

    int nblkN = (NN + 255) / 256;

    // atomic-free counting sort -> CSR
    k_hist<<<NB, 256, 0, stream>>>(ei, histG);
    k_bscan<<<CB, NB, 0, stream>>>(histG, total);
    k_cbase<<<1, 1024, 0, stream>>>(total, cbase);
    k_cscatter<<<NB, 256, 0, stream>>>(ei, histG, cbase, metaS);
    k_fine<<<CB, 256, 0, stream>>>(metaS, cbase, cnt, offs, col);
    k_dinv<<<nblkN, 256, 0, stream>>>(cnt, dinv);

    // layer 1
    k_aggx<<<NN / 16, 256, 0, stream>>>(x, offs, cnt, col, dinv, wgt, agg);
    k_l1<<<(NN + L1R - 1) / L1R, 128, 0, stream>>>(agg, W1, b1, bn1g, bn1b, bn1m, bn1v, bufA);

    // layer 2
    k_mm<<<(NN + 63) / 64, 256, 0, stream>>>(bufA, W2, tB);
    k_agg<<<NN / 8, 256, 0, stream>>>(tB, offs, cnt, col, wgt, dinv,
                                      b2, bn2g, bn2b, bn2m, bn2v, bufA);

    // layer 3
    k_mm<<<(NN + 63) / 64, 256, 0, stream>>>(bufA, W3, tB);
    k_agg<<<NN / 8, 256, 0, stream>>>(tB, offs, cnt, col, wgt, dinv,
                                      b3, bn3g, bn3b, bn3m, bn3v, bufA);

    // pool + head
    k_pool<<<PBLK, 128, 0, stream>>>(bufA, batch, gsum, gcnt);
    k_head<<<1, 128, 0, stream>>>(gsum, gcnt, linW, linb, out);
}

// Round 5
// 442.796 us; speedup vs baseline: 1.9670x; 1.0402x over previous
//
#include <hip/hip_runtime.h>

#define NN 100000
#define EE 1600000
#define GG 64
#define HH 128
#define BN_EPS 1e-5f

#define CB 782            // coarse buckets = ceil(NN/128), bucket = dst>>7
#define NB 256            // tiles for hist/scatter passes
#define TILE 6250         // EE / NB exactly

typedef unsigned short ushort_t;

// round-to-nearest-even fp32 -> bf16 (finite values)
static __device__ inline ushort_t f2bf(float f) {
    unsigned u = __float_as_uint(f);
    unsigned r = (u + 0x7FFF + ((u >> 16) & 1)) >> 16;
    return (ushort_t)r;
}
static __device__ inline float bf2f(ushort_t b) {
    return __uint_as_float(((unsigned)b) << 16);
}

// ---------------- graph prep: atomic-free two-level counting sort ----------------

__global__ __launch_bounds__(256) void k_hist(const int* __restrict__ ei,
                                              int* __restrict__ histG) {
    __shared__ int h[CB];
    int t = threadIdx.x;
    for (int i = t; i < CB; i += 256) h[i] = 0;
    __syncthreads();
    int e0 = blockIdx.x * TILE;
    for (int i = t; i < TILE; i += 256) {
        int d = ei[EE + e0 + i];
        atomicAdd(&h[d >> 7], 1);
    }
    __syncthreads();
    for (int i = t; i < CB; i += 256) histG[blockIdx.x * CB + i] = h[i];
}

__global__ __launch_bounds__(NB) void k_bscan(int* __restrict__ histG,
                                              int* __restrict__ total) {
    __shared__ int sh[NB];
    int t = threadIdx.x;
    int c = blockIdx.x;
    sh[t] = histG[t * CB + c];
    __syncthreads();
    for (int d = 1; d < NB; d <<= 1) {
        int x = (t >= d) ? sh[t - d] : 0;
        __syncthreads();
        sh[t] += x;
        __syncthreads();
    }
    histG[t * CB + c] = (t > 0) ? sh[t - 1] : 0;
    if (t == NB - 1) total[c] = sh[NB - 1];
}

__global__ __launch_bounds__(1024) void k_cbase(const int* __restrict__ total,
                                                int* __restrict__ cbase) {
    __shared__ int sh[1024];
    int t = threadIdx.x;
    sh[t] = (t < CB) ? total[t] : 0;
    __syncthreads();
    for (int d = 1; d < 1024; d <<= 1) {
        int x = (t >= d) ? sh[t - d] : 0;
        __syncthreads();
        sh[t] += x;
        __syncthreads();
    }
    if (t < CB) cbase[t] = (t > 0) ? sh[t - 1] : 0;
    if (t == CB - 1) cbase[CB] = sh[t];   // == EE
}

__global__ __launch_bounds__(256) void k_cscatter(const int* __restrict__ ei,
                                                  const int* __restrict__ histG,
                                                  const int* __restrict__ cbase,
                                                  int* __restrict__ metaS) {
    __shared__ int base_l[CB];
    __shared__ int cur_l[CB];
    int t = threadIdx.x;
    int b = blockIdx.x;
    for (int i = t; i < CB; i += 256) {
        base_l[i] = cbase[i] + histG[b * CB + i];
        cur_l[i] = 0;
    }
    __syncthreads();
    int e0 = b * TILE;
    for (int i = t; i < TILE; i += 256) {
        int s = ei[e0 + i];
        int d = ei[EE + e0 + i];
        int c = d >> 7;
        int p = base_l[c] + atomicAdd(&cur_l[c], 1);
        metaS[p] = s | ((d & 127) << 17);
    }
}

// pass D: fine histogram, cnt/offs, sorted col; dinv fused at the end
__global__ __launch_bounds__(256) void k_fine(const int* __restrict__ metaS,
                                              const int* __restrict__ cbase,
                                              int* __restrict__ cnt,
                                              int* __restrict__ offs,
                                              int* __restrict__ col,
                                              float* __restrict__ dinv) {
    __shared__ int hist[128];
    __shared__ int scn[128];
    __shared__ int cur[128];
    int t = threadIdx.x;
    int c = blockIdx.x;
    int lo = cbase[c], hi = cbase[c + 1];
    if (t < 128) hist[t] = 0;
    __syncthreads();
    for (int r = lo + t; r < hi; r += 256) atomicAdd(&hist[metaS[r] >> 17], 1);
    __syncthreads();
    if (t < 128) scn[t] = hist[t];
    __syncthreads();
    for (int d = 1; d < 128; d <<= 1) {
        int x = (t >= d && t < 128) ? scn[t - d] : 0;
        __syncthreads();
        if (t < 128) scn[t] += x;
        __syncthreads();
    }
    if (t < 128) {
        int excl = (t > 0) ? scn[t - 1] : 0;
        cur[t] = excl;
        int node = c * 128 + t;
        if (node < NN) {
            cnt[node] = hist[t];
            offs[node] = lo + excl;
            dinv[node] = rsqrtf((float)(hist[t] + 1));   // +1 self loop
        }
    }
    __syncthreads();
    for (int r = lo + t; r < hi; r += 256) {
        int pk = metaS[r];
        int s = pk & 0x1FFFF;
        int idx = atomicAdd(&cur[pk >> 17], 1);
        col[lo + idx] = s;
    }
}

// ---------------- layer 1 aggregate (3-dim) + weight materialize ----------------
// 16-lane group per node: lane-parallel edges, shfl-xor reduction

__global__ __launch_bounds__(256) void k_aggx(const float* __restrict__ x,
                                              const int* __restrict__ offs,
                                              const int* __restrict__ cnt,
                                              const int* __restrict__ col,
                                              const float* __restrict__ dinv,
                                              float* __restrict__ wgt,
                                              float4* __restrict__ agg) {
    int tid = threadIdx.x;
    int wave = tid >> 6;
    int lane = tid & 63;
    int grp = lane >> 4;
    int l = lane & 15;
    int n = blockIdx.x * 16 + wave * 4 + grp;    // NN % 16 == 0
    float dv = dinv[n];
    int base = offs[n], cn = cnt[n];
    float a0 = 0.f, a1 = 0.f, a2 = 0.f;
    for (int i = l; i < cn; i += 16) {
        int s = col[base + i];
        float w = dinv[s] * dv;
        wgt[base + i] = w;
        a0 += w * x[s * 3 + 0];
        a1 += w * x[s * 3 + 1];
        a2 += w * x[s * 3 + 2];
    }
#pragma unroll
    for (int off = 8; off >= 1; off >>= 1) {
        a0 += __shfl_xor(a0, off, 16);
        a1 += __shfl_xor(a1, off, 16);
        a2 += __shfl_xor(a2, off, 16);
    }
    if (l == 0) {
        float w0 = dv * dv;
        a0 += w0 * x[n * 3 + 0];
        a1 += w0 * x[n * 3 + 1];
        a2 += w0 * x[n * 3 + 2];
        agg[n] = make_float4(a0, a1, a2, 0.f);
    }
}

// ---------------- fused layer1 + layer2 matmul: t2 = relu(bn(agg@W1)) @ W2, bf16 out ----

__global__ __launch_bounds__(256) void k_mml1(const float4* __restrict__ agg,
                                              const float* __restrict__ W1,
                                              const float* __restrict__ b1,
                                              const float* __restrict__ g1,
                                              const float* __restrict__ bb1,
                                              const float* __restrict__ m1,
                                              const float* __restrict__ v1,
                                              const float* __restrict__ W2,
                                              ushort_t* __restrict__ outB) {
    __shared__ float xs[64][132];
    __shared__ float4 ag[64];
    int tid = threadIdx.x;
    int row0 = blockIdx.x * 64;
    if (tid < 64) {
        int gr = row0 + tid;
        ag[tid] = (gr < NN) ? agg[gr] : make_float4(0.f, 0.f, 0.f, 0.f);
    }
    __syncthreads();
    // build h1 tile: c fixed per thread = tid&127, rows r = 2i + (tid>>7)
    {
        int c = tid & 127;
        int rh = tid >> 7;
        float w0 = W1[c], w1 = W1[128 + c], w2 = W1[256 + c];
        float sc = g1[c] * rsqrtf(v1[c] + BN_EPS);
        float sh = (b1[c] - m1[c]) * sc + bb1[c];
#pragma unroll
        for (int i = 0; i < 32; i++) {
            int r = 2 * i + rh;
            float4 a = ag[r];
            float t = a.x * w0 + a.y * w1 + a.z * w2;
            xs[r][c] = fmaxf(t * sc + sh, 0.f);
        }
    }
    __syncthreads();

    int tx = tid & 31;
    int ty = tid >> 5;
    float acc[8][4];
#pragma unroll
    for (int i = 0; i < 8; i++)
#pragma unroll
        for (int j = 0; j < 4; j++) acc[i][j] = 0.f;

    const float* Wp = W2 + tx * 4;
#pragma unroll 4
    for (int k = 0; k < 128; k++) {
        float4 w = *(const float4*)&Wp[k * HH];
#pragma unroll
        for (int i = 0; i < 8; i++) {
            float xv = xs[ty * 8 + i][k];
            acc[i][0] += xv * w.x;
            acc[i][1] += xv * w.y;
            acc[i][2] += xv * w.z;
            acc[i][3] += xv * w.w;
        }
    }
#pragma unroll
    for (int i = 0; i < 8; i++) {
        int gr = row0 + ty * 8 + i;
        if (gr < NN) {
            ushort4 o;
            o.x = f2bf(acc[i][0]);
            o.y = f2bf(acc[i][1]);
            o.z = f2bf(acc[i][2]);
            o.w = f2bf(acc[i][3]);
            *(ushort4*)&outB[(size_t)gr * HH + tx * 4] = o;
        }
    }
}

// ---------------- dense 128x128 matmul, bf16 in / bf16 out ----------------

__global__ __launch_bounds__(256) void k_mm(const ushort_t* __restrict__ xin,
                                            const float* __restrict__ W,
                                            ushort_t* __restrict__ outB) {
    __shared__ float xs[64][132];
    int tid = threadIdx.x;
    int tx = tid & 31;
    int ty = tid >> 5;
    int row0 = blockIdx.x * 64;
#pragma unroll
    for (int i = 0; i < 4; i++) {
        int idx8 = i * 256 + tid;        // 0..1023 ushort8 slots
        int r = idx8 >> 4;               // 16 slots per row
        int k8 = (idx8 & 15) * 8;
        int gr = row0 + r;
        int4 pk = (gr < NN) ? *(const int4*)&xin[(size_t)gr * HH + k8]
                            : make_int4(0, 0, 0, 0);
        float* dst = &xs[r][k8];
        dst[0] = __uint_as_float(((unsigned)pk.x) << 16);
        dst[1] = __uint_as_float(((unsigned)pk.x) & 0xFFFF0000u);
        dst[2] = __uint_as_float(((unsigned)pk.y) << 16);
        dst[3] = __uint_as_float(((unsigned)pk.y) & 0xFFFF0000u);
        dst[4] = __uint_as_float(((unsigned)pk.z) << 16);
        dst[5] = __uint_as_float(((unsigned)pk.z) & 0xFFFF0000u);
        dst[6] = __uint_as_float(((unsigned)pk.w) << 16);
        dst[7] = __uint_as_float(((unsigned)pk.w) & 0xFFFF0000u);
    }
    __syncthreads();
    float acc[8][4];
#pragma unroll
    for (int i = 0; i < 8; i++)
#pragma unroll
        for (int j = 0; j < 4; j++) acc[i][j] = 0.f;

    const float* Wp = W + tx * 4;
#pragma unroll 4
    for (int k = 0; k < 128; k++) {
        float4 w = *(const float4*)&Wp[k * HH];
#pragma unroll
        for (int i = 0; i < 8; i++) {
            float xv = xs[ty * 8 + i][k];
            acc[i][0] += xv * w.x;
            acc[i][1] += xv * w.y;
            acc[i][2] += xv * w.z;
            acc[i][3] += xv * w.w;
        }
    }
#pragma unroll
    for (int i = 0; i < 8; i++) {
        int gr = row0 + ty * 8 + i;
        if (gr < NN) {
            ushort4 o;
            o.x = f2bf(acc[i][0]);
            o.y = f2bf(acc[i][1]);
            o.z = f2bf(acc[i][2]);
            o.w = f2bf(acc[i][3]);
            *(ushort4*)&outB[(size_t)gr * HH + tx * 4] = o;
        }
    }
}

// ---------------- gather-aggregate (bf16 rows) + bias + BN + ReLU, bf16 out ------
// half-wave (32 lanes) per node, lane holds 4 bf16 channels (8B), fp32 accum

__global__ __launch_bounds__(256) void k_agg(const ushort_t* __restrict__ t,
                                             const int* __restrict__ offs,
                                             const int* __restrict__ cnt,
                                             const int* __restrict__ col,
                                             const float* __restrict__ wgt,
                                             const float* __restrict__ dinv,
                                             const float* __restrict__ bias,
                                             const float* __restrict__ g,
                                             const float* __restrict__ bb,
                                             const float* __restrict__ m,
                                             const float* __restrict__ v,
                                             ushort_t* __restrict__ out) {
    int wave = threadIdx.x >> 6;
    int lane = threadIdx.x & 63;
    int half = lane >> 5;
    int l = lane & 31;
    int d = blockIdx.x * 8 + wave * 2 + half;    // NN % 8 == 0
    int c0 = l * 4;
    float dv = dinv[d];
    float w0 = dv * dv;
    ushort4 selfR = *(const ushort4*)&t[(size_t)d * HH + c0];
    float4 acc;
    acc.x = bf2f(selfR.x) * w0; acc.y = bf2f(selfR.y) * w0;
    acc.z = bf2f(selfR.z) * w0; acc.w = bf2f(selfR.w) * w0;
    int base = offs[d], cn = cnt[d];
    for (int ib = 0; ib < cn; ib += 32) {
        int i = ib + l;
        int s = 0;
        float w = 0.f;
        if (i < cn) {
            s = col[base + i];
            w = wgt[base + i];
        }
        int lim = min(32, cn - ib);
#pragma unroll 8
        for (int j = 0; j < lim; j++) {
            int ss = __shfl(s, j, 32);
            float ww = __shfl(w, j, 32);
            ushort4 tv = *(const ushort4*)&t[(size_t)ss * HH + c0];
            acc.x += ww * bf2f(tv.x);
            acc.y += ww * bf2f(tv.y);
            acc.z += ww * bf2f(tv.z);
            acc.w += ww * bf2f(tv.w);
        }
    }
    float4 gg = *(const float4*)&g[c0];
    float4 vv = *(const float4*)&v[c0];
    float4 mm = *(const float4*)&m[c0];
    float4 bv = *(const float4*)&bb[c0];
    float4 bi = *(const float4*)&bias[c0];
    float sc0 = gg.x * rsqrtf(vv.x + BN_EPS);
    float sc1 = gg.y * rsqrtf(vv.y + BN_EPS);
    float sc2 = gg.z * rsqrtf(vv.z + BN_EPS);
    float sc3 = gg.w * rsqrtf(vv.w + BN_EPS);
    ushort4 o;
    o.x = f2bf(fmaxf(acc.x * sc0 + (bi.x - mm.x) * sc0 + bv.x, 0.f));
    o.y = f2bf(fmaxf(acc.y * sc1 + (bi.y - mm.y) * sc1 + bv.y, 0.f));
    o.z = f2bf(fmaxf(acc.z * sc2 + (bi.z - mm.z) * sc2 + bv.z, 0.f));
    o.w = f2bf(fmaxf(acc.w * sc3 + (bi.w - mm.w) * sc3 + bv.w, 0.f));
    *(ushort4*)&out[(size_t)d * HH + c0] = o;
}

// ---------------- mean pool (bf16 in, fp32 accum) ----------------

#define PBLK 2048
__global__ void k_pool(const ushort_t* __restrict__ h, const int* __restrict__ batch,
                       float* __restrict__ gsum, int* __restrict__ gcnt) {
    int c = threadIdx.x;  // 128
    int per = (NN + PBLK - 1) / PBLK;
    int n0 = blockIdx.x * per;
    int n1 = min(NN, n0 + per);
    if (n0 >= NN) return;
    float acc = 0.f;
    int cur = batch[n0];
    int count = 0;
    for (int n = n0; n < n1; n++) {
        int gr = batch[n];
        if (gr != cur) {
            atomicAdd(&gsum[cur * HH + c], acc);
            if (c == 0) atomicAdd(&gcnt[cur], count);
            acc = 0.f; count = 0; cur = gr;
        }
        acc += bf2f(h[(size_t)n * HH + c]);
        count++;
    }
    atomicAdd(&gsum[cur * HH + c], acc);
    if (c == 0) atomicAdd(&gcnt[cur], count);
}

__global__ void k_head(const float* __restrict__ gsum, const int* __restrict__ gcnt,
                       const float* __restrict__ linW, const float* __restrict__ linb,
                       float* __restrict__ out) {
    int t = threadIdx.x;        // 128 = 64 graphs x 2 outputs
    int gr = t >> 1, j = t & 1;
    float inv = 1.0f / fmaxf((float)gcnt[gr], 1.0f);
    float acc = 0.f;
    for (int c = 0; c < HH; c++) acc += gsum[gr * HH + c] * linW[c * 2 + j];
    out[t] = acc * inv + linb[j];
}

// ---------------- host launch ----------------

static inline size_t al256(size_t x) { return (x + 255) & ~(size_t)255; }

extern "C" void kernel_launch(void* const* d_in, const int* in_sizes, int n_in,
                              void* d_out, int out_size, void* d_ws, size_t ws_size,
                              hipStream_t stream) {
    const float* x    = (const float*)d_in[0];
    const int*   ei   = (const int*)d_in[1];
    const int*   batch= (const int*)d_in[2];
    const float* W1   = (const float*)d_in[3];
    const float* b1   = (const float*)d_in[4];
    const float* W2   = (const float*)d_in[5];
    const float* b2   = (const float*)d_in[6];
    const float* W3   = (const float*)d_in[7];
    const float* b3   = (const float*)d_in[8];
    const float* linW = (const float*)d_in[9];
    const float* linb = (const float*)d_in[10];
    const float* bn1g = (const float*)d_in[11];
    const float* bn1b = (const float*)d_in[12];
    const float* bn1m = (const float*)d_in[13];
    const float* bn1v = (const float*)d_in[14];
    const float* bn2g = (const float*)d_in[15];
    const float* bn2b = (const float*)d_in[16];
    const float* bn2m = (const float*)d_in[17];
    const float* bn2v = (const float*)d_in[18];
    const float* bn3g = (const float*)d_in[19];
    const float* bn3b = (const float*)d_in[20];
    const float* bn3m = (const float*)d_in[21];
    const float* bn3v = (const float*)d_in[22];
    float* out = (float*)d_out;

    char* ws = (char*)d_ws;
    size_t off = 0;
    int*    histG  = (int*)(ws + off);    off += al256((size_t)NB * CB * 4);
    int*    total  = (int*)(ws + off);    off += al256((size_t)CB * 4);
    int*    cbase  = (int*)(ws + off);    off += al256((size_t)(CB + 1) * 4);
    int*    cnt    = (int*)(ws + off);    off += al256((size_t)NN * 4);
    int*    offs   = (int*)(ws + off);    off += al256((size_t)NN * 4);
    float*  dinv   = (float*)(ws + off);  off += al256((size_t)NN * 4);
    int*    col    = (int*)(ws + off);    off += al256((size_t)EE * 4);
    float*  wgt    = (float*)(ws + off);  off += al256((size_t)EE * 4);
    float4* agg    = (float4*)(ws + off); off += al256((size_t)NN * 16);
    char*   bufA   = (char*)(ws + off);   off += al256((size_t)NN * HH * 2);
    char*   bufB   = (char*)(ws + off);   off += al256((size_t)NN * HH * 4);
    float*  gsum   = (float*)(ws + off);  off += (size_t)GG * HH * 4;
    int*    gcnt   = (int*)(ws + off);    off += al256((size_t)GG * 4);

    // metaS (coarse-sorted packed edges, 6.4MB) and tB (bf16 t-buffer, 25.6MB)
    // both overlay bufB: metaS fully consumed by k_fine before first t write.
    int* metaS = (int*)bufB;
    ushort_t* tB = (ushort_t*)bufB;
    ushort_t* hB = (ushort_t*)bufA;       // bf16 h buffer (layer-2/3 outputs)

    hipMemsetAsync(gsum, 0, (size_t)GG * HH * 4 + (size_t)GG * 4, stream);

    // atomic-free counting sort -> CSR (+ dinv fused into k_fine)
    k_hist<<<NB, 256, 0, stream>>>(ei, histG);
    k_bscan<<<CB, NB, 0, stream>>>(histG, total);
    k_cbase<<<1, 1024, 0, stream>>>(total, cbase);
    k_cscatter<<<NB, 256, 0, stream>>>(ei, histG, cbase, metaS);
    k_fine<<<CB, 256, 0, stream>>>(metaS, cbase, cnt, offs, col, dinv);

    // layer 1 aggregate in input space (3-dim) + materialize weights
    k_aggx<<<NN / 16, 256, 0, stream>>>(x, offs, cnt, col, dinv, wgt, agg);

    // fused layer1 + layer2 matmul: t2 = relu(bn1(agg@W1)) @ W2
    k_mml1<<<(NN + 63) / 64, 256, 0, stream>>>(agg, W1, b1, bn1g, bn1b, bn1m, bn1v,
                                               W2, tB);
    k_agg<<<NN / 8, 256, 0, stream>>>(tB, offs, cnt, col, wgt, dinv,
                                      b2, bn2g, bn2b, bn2m, bn2v, hB);

    // layer 3
    k_mm<<<(NN + 63) / 64, 256, 0, stream>>>(hB, W3, tB);
    k_agg<<<NN / 8, 256, 0, stream>>>(tB, offs, cnt, col, wgt, dinv,
                                      b3, bn3g, bn3b, bn3m, bn3v, hB);

    // pool + head
    k_pool<<<PBLK, 128, 0, stream>>>(hB, batch, gsum, gcnt);
    k_head<<<1, 128, 0, stream>>>(gsum, gcnt, linW, linb, out);
}